// Round 1
// baseline (12.272 us; speedup 1.0000x reference)
//
#include <hip/hip_runtime.h>
#include <math.h>

// Cl(3,0) geometric product: e_i * e_j = SIGN[i][j] * e_{i XOR j}
// Blade order: 0:1, 1:e1, 2:e2, 3:e12, 4:e3, 5:e13, 6:e23, 7:e123
__device__ __constant__ float SIGN8[8][8] = {
    { 1, 1, 1, 1, 1, 1, 1, 1},
    { 1, 1, 1, 1, 1, 1, 1, 1},
    { 1,-1, 1,-1, 1,-1, 1,-1},
    { 1,-1, 1,-1, 1,-1, 1,-1},
    { 1,-1,-1, 1, 1,-1,-1, 1},
    { 1,-1,-1, 1, 1,-1,-1, 1},
    { 1, 1,-1,-1, 1, 1,-1,-1},
    { 1, 1,-1,-1, 1, 1,-1,-1},
};

__device__ __forceinline__ void gp8(const float* a, const float* b, float* out) {
    float r[8] = {0.f, 0.f, 0.f, 0.f, 0.f, 0.f, 0.f, 0.f};
#pragma unroll
    for (int i = 0; i < 8; ++i) {
#pragma unroll
        for (int j = 0; j < 8; ++j) {
            r[i ^ j] += SIGN8[i][j] * a[i] * b[j];
        }
    }
#pragma unroll
    for (int k = 0; k < 8; ++k) out[k] = r[k];
}

// Rotor from bivector coords (slots 3,5,6): R = cos(t) + sin(t)/t * (-B/2)
__device__ __forceinline__ void make_rotor(const float* bv, float* R, float* Rrev) {
    float h3 = -0.5f * bv[0];
    float h5 = -0.5f * bv[1];
    float h6 = -0.5f * bv[2];
    float t2 = h3 * h3 + h5 * h5 + h6 * h6;
    float t  = sqrtf(t2);
    float s  = (t > 1e-12f) ? (sinf(t) / t) : 1.0f;
#pragma unroll
    for (int k = 0; k < 8; ++k) { R[k] = 0.f; Rrev[k] = 0.f; }
    R[0] = cosf(t);
    R[3] = s * h3;
    R[5] = s * h5;
    R[6] = s * h6;
    // reverse: grade0 -> +, grade2 -> -
    Rrev[0] = R[0];
    Rrev[3] = -R[3];
    Rrev[5] = -R[5];
    Rrev[6] = -R[6];
}

// 3 stages x 3 nodes; thread i owns node i, whole multivector in registers.
__global__ void __launch_bounds__(64) morph_pipeline_kernel(
    const float* __restrict__ basis_mvs,  // [3][8]
    const float* __restrict__ global_bv,  // [3][3]
    const float* __restrict__ twist_bvs,  // [3][3][3]
    const float* __restrict__ log_scale,  // [3][3]
    float* __restrict__ out)              // [24 final x] ++ [3][3][8] intermediates
{
    const int node = threadIdx.x;
    if (node >= 3) return;

    float x[8];
#pragma unroll
    for (int k = 0; k < 8; ++k) x[k] = basis_mvs[node * 8 + k];

    float R[8], Rrev[8], T[8], Trev[8], tmp[8];

    for (int s = 0; s < 3; ++s) {
        // Global rotor (shared across nodes; recomputed per thread, it's 3 lanes)
        make_rotor(&global_bv[s * 3], R, Rrev);
        gp8(R, x, tmp);
        gp8(tmp, Rrev, x);

        // Per-node twist rotor
        make_rotor(&twist_bvs[(s * 3 + node) * 3], T, Trev);
        gp8(T, x, tmp);
        gp8(tmp, Trev, x);

        // Dynamic scale
        float ls = log_scale[s * 3 + node];
        ls = fminf(fmaxf(ls, -3.0f), 3.0f);
        float sc = expf(ls);
#pragma unroll
        for (int k = 0; k < 8; ++k) x[k] *= sc;

        // intermediates[s][node][:]
#pragma unroll
        for (int k = 0; k < 8; ++k) out[24 + (s * 3 + node) * 8 + k] = x[k];
    }

    // final x[node][:]
#pragma unroll
    for (int k = 0; k < 8; ++k) out[node * 8 + k] = x[k];
}

extern "C" void kernel_launch(void* const* d_in, const int* in_sizes, int n_in,
                              void* d_out, int out_size, void* d_ws, size_t ws_size,
                              hipStream_t stream) {
    const float* basis_mvs = (const float*)d_in[0];
    const float* global_bv = (const float*)d_in[1];
    const float* twist_bvs = (const float*)d_in[2];
    const float* log_scale = (const float*)d_in[3];
    float* out = (float*)d_out;

    morph_pipeline_kernel<<<1, 64, 0, stream>>>(basis_mvs, global_bv, twist_bvs,
                                                log_scale, out);
}

// Round 2
// 9.517 us; speedup vs baseline: 1.2895x; 1.2895x over previous
//
#include <hip/hip_runtime.h>
#include <math.h>

// Cl(3,0) geometric product: e_i * e_j = sign(i,j) * e_{i XOR j}
// Blade order: 0:1, 1:e1, 2:e2, 3:e12, 4:e3, 5:e13, 6:e23, 7:e123
// constexpr so the compiler folds signs into FMA neg-modifiers (no loads).
__device__ __forceinline__ void gp8(const float* a, const float* b, float* out) {
    constexpr float S[8][8] = {
        { 1, 1, 1, 1, 1, 1, 1, 1},
        { 1, 1, 1, 1, 1, 1, 1, 1},
        { 1,-1, 1,-1, 1,-1, 1,-1},
        { 1,-1, 1,-1, 1,-1, 1,-1},
        { 1,-1,-1, 1, 1,-1,-1, 1},
        { 1,-1,-1, 1, 1,-1,-1, 1},
        { 1, 1,-1,-1, 1, 1,-1,-1},
        { 1, 1,-1,-1, 1, 1,-1,-1},
    };
    float r[8] = {0.f, 0.f, 0.f, 0.f, 0.f, 0.f, 0.f, 0.f};
#pragma unroll
    for (int i = 0; i < 8; ++i) {
#pragma unroll
        for (int j = 0; j < 8; ++j) {
            r[i ^ j] += S[i][j] * a[i] * b[j];
        }
    }
#pragma unroll
    for (int k = 0; k < 8; ++k) out[k] = r[k];
}

// Rotor from bivector coords (slots 3,5,6): R = cos(t) + sin(t)/t * (-B/2)
__device__ __forceinline__ void make_rotor(const float* bv, float* R, float* Rrev) {
    float h3 = -0.5f * bv[0];
    float h5 = -0.5f * bv[1];
    float h6 = -0.5f * bv[2];
    float t2 = h3 * h3 + h5 * h5 + h6 * h6;
    float t  = __builtin_sqrtf(t2);
    // sin(t)/t, guarded at t->0 (inputs are ~0.01-scale so t is tiny but nonzero)
    float s  = (t > 1e-12f) ? (__sinf(t) / t) : 1.0f;
#pragma unroll
    for (int k = 0; k < 8; ++k) { R[k] = 0.f; Rrev[k] = 0.f; }
    float c = __cosf(t);
    R[0] = c;
    R[3] = s * h3;
    R[5] = s * h5;
    R[6] = s * h6;
    // reverse: grade0 -> +, grade2 -> -
    Rrev[0] = c;
    Rrev[3] = -R[3];
    Rrev[5] = -R[5];
    Rrev[6] = -R[6];
}

// 3 stages x 3 nodes; thread i owns node i, whole multivector in registers.
__global__ void __launch_bounds__(64) morph_pipeline_kernel(
    const float* __restrict__ basis_mvs,  // [3][8]
    const float* __restrict__ global_bv,  // [3][3]
    const float* __restrict__ twist_bvs,  // [3][3][3]
    const float* __restrict__ log_scale,  // [3][3]
    float* __restrict__ out)              // [24 final x] ++ [3][3][8] intermediates
{
    const int node = threadIdx.x;
    if (node >= 3) return;

    float x[8];
#pragma unroll
    for (int k = 0; k < 8; ++k) x[k] = basis_mvs[node * 8 + k];

    float R[8], Rrev[8], T[8], Trev[8], tmp[8];

#pragma unroll
    for (int s = 0; s < 3; ++s) {
        // Global rotor (shared across nodes; recomputed per lane, only 3 lanes)
        make_rotor(&global_bv[s * 3], R, Rrev);
        gp8(R, x, tmp);
        gp8(tmp, Rrev, x);

        // Per-node twist rotor
        make_rotor(&twist_bvs[(s * 3 + node) * 3], T, Trev);
        gp8(T, x, tmp);
        gp8(tmp, Trev, x);

        // Dynamic scale
        float ls = log_scale[s * 3 + node];
        ls = fminf(fmaxf(ls, -3.0f), 3.0f);
        float sc = __expf(ls);
#pragma unroll
        for (int k = 0; k < 8; ++k) x[k] *= sc;

        // intermediates[s][node][:]
#pragma unroll
        for (int k = 0; k < 8; ++k) out[24 + (s * 3 + node) * 8 + k] = x[k];
    }

    // final x[node][:]
#pragma unroll
    for (int k = 0; k < 8; ++k) out[node * 8 + k] = x[k];
}

extern "C" void kernel_launch(void* const* d_in, const int* in_sizes, int n_in,
                              void* d_out, int out_size, void* d_ws, size_t ws_size,
                              hipStream_t stream) {
    const float* basis_mvs = (const float*)d_in[0];
    const float* global_bv = (const float*)d_in[1];
    const float* twist_bvs = (const float*)d_in[2];
    const float* log_scale = (const float*)d_in[3];
    float* out = (float*)d_out;

    morph_pipeline_kernel<<<1, 64, 0, stream>>>(basis_mvs, global_bv, twist_bvs,
                                                log_scale, out);
}